// Round 17
// baseline (379.604 us; speedup 1.0000x reference)
//
#include <hip/hip_runtime.h>
#include <math.h>

#define DEPTH 18
#define NINT ((1 << (DEPTH - 1)) - 1)      // internal nodes = 131071
#define NVOCAB 50000
#define SAW 520                             // sA row stride: [x|hs|h1|h2] + pad
#define KTS 9                               // Bfrag ktile stride (pow2-aliasing fix, r10)
#define NEMB (NVOCAB * 128 / 4 / 256)       // 6250 embed-convert blocks

typedef unsigned short bf16raw;
typedef __bf16 bf16x8 __attribute__((ext_vector_type(8)));
typedef float f32x4 __attribute__((ext_vector_type(4)));
typedef short short8 __attribute__((ext_vector_type(8)));

__device__ __forceinline__ float sigm(float x) { return 1.0f / (1.0f + __expf(-x)); }
__device__ __forceinline__ float fast_tanh(float x) {
    float t = __expf(2.0f * x);
    return 1.0f - 2.0f / (t + 1.0f);
}

__device__ __forceinline__ float bf2f(bf16raw u) {
    union { unsigned int i; float f; } v;
    v.i = ((unsigned int)u) << 16;
    return v.f;
}
__device__ __forceinline__ bf16raw f2bf(float f) {
    union { float f; unsigned int i; } v;
    v.f = f;
    unsigned int r = v.i + 0x7FFFu + ((v.i >> 16) & 1u);  // RNE
    return (bf16raw)(r >> 16);
}

#define SB() __builtin_amdgcn_sched_barrier(0)

// ---------------------------------------------------------------------------
// k_prep_all: ONE dispatch for all prep (r15).
// ---------------------------------------------------------------------------
__global__ __launch_bounds__(256) void k_prep_all(
    const float* __restrict__ embeds,
    const float* __restrict__ Wix, const float* __restrict__ bix,
    const float* __restrict__ Wih, const float* __restrict__ bih,
    const float* __restrict__ Wfx, const float* __restrict__ bfx,
    const float* __restrict__ Wfh, const float* __restrict__ bfh,
    const float* __restrict__ Wox, const float* __restrict__ box_,
    const float* __restrict__ Woh, const float* __restrict__ boh,
    const float* __restrict__ Wux, const float* __restrict__ bux,
    const float* __restrict__ Wuh, const float* __restrict__ buh,
    const float* __restrict__ Wout,
    bf16raw* __restrict__ embeds_bf,
    bf16raw* __restrict__ Bfrag, bf16raw* __restrict__ WoutFrag,
    float* __restrict__ bias_cat, float* __restrict__ partials)
{
    const int bid = blockIdx.x;
    const int t = threadIdx.x;
    if (bid < NEMB) {
        const int i = bid * 256 + t;
        float4 v = ((const float4*)embeds)[i];
        ushort4 o;
        o.x = f2bf(v.x); o.y = f2bf(v.y); o.z = f2bf(v.z); o.w = f2bf(v.w);
        ((ushort4*)embeds_bf)[i] = o;
        return;
    }
    if (bid == NEMB + 528) {
#pragma unroll
        for (int s = 0; s < 4; ++s) partials[t + 256 * s] = 0.f;
        return;
    }
    const int j = bid - NEMB;        // 0..527
    if (j >= 512) {
        const int col = j - 512;     // 0..15 WoutFrag col
        for (int k = t; k < 128; k += 256) {
            float v = (col < 5) ? Wout[col * 128 + k] : 0.f;
            WoutFrag[((k >> 5) * 64 + ((k >> 3) & 3) * 16 + col) * 8 + (k & 7)] = f2bf(v);
        }
        return;
    }
    const int gate = j >> 7, jj = j & 127;
    const float *Wx, *Wh, *bx, *bh;
    switch (gate) {
        case 0: Wx = Wix; Wh = Wih; bx = bix;  bh = bih; break;
        case 1: Wx = Wux; Wh = Wuh; bx = bux;  bh = buh; break;
        case 2: Wx = Wox; Wh = Woh; bx = box_; bh = boh; break;
        default: Wx = Wfx; Wh = Wfh; bx = bfx; bh = bfh; break;
    }
    const int coltile = (j >> 4) & 7, lr = j & 15;
    for (int k = t; k < 256; k += 256) {
        float v = (k < 128) ? Wx[jj * 128 + k] : Wh[jj * 128 + (k - 128)];
        const int idx = (((gate * 8 + coltile) * KTS + (k >> 5)) * 64
                         + ((k >> 3) & 3) * 16 + lr) * 8 + (k & 7);
        Bfrag[idx] = f2bf(v);
    }
    if (t == 0) bias_cat[j] = bx[jj] + bh[jj];
}

// ---------------------------------------------------------------------------
// k_leafpre burst helpers (64-row variant).
// ---------------------------------------------------------------------------
template<int CB>
__device__ __forceinline__ void lp_burst(const bf16raw* __restrict__ bfbase, int wcol,
                                         bf16x8 (&bb)[16])
{
#pragma unroll
    for (int kt = 0; kt < 4; ++kt)
#pragma unroll
        for (int j = 0; j < 4; ++j)
            bb[kt * 4 + j] = *(const bf16x8*)(bfbase +
                    (long)(((CB * 8 + (wcol >> 4) + j) * KTS + kt) * 512));
}

__device__ __forceinline__ void lp_mfma_all(const bf16raw* __restrict__ sA, int wrow,
                                            int lrow, int lquad,
                                            bf16x8 (&bb)[16], f32x4 (&acc)[2][4])
{
#pragma unroll
    for (int kt = 0; kt < 4; ++kt) {
        bf16x8 af[2];
#pragma unroll
        for (int i = 0; i < 2; ++i)
            af[i] = *(const bf16x8*)&sA[(wrow + i * 16 + lrow) * 136 + kt * 32 + lquad * 8];
#pragma unroll
        for (int i = 0; i < 2; ++i)
#pragma unroll
            for (int j = 0; j < 4; ++j)
                acc[i][j] = __builtin_amdgcn_mfma_f32_16x16x32_bf16(af[i], bb[kt * 4 + j], acc[i][j], 0, 0, 0);
    }
}

template<int CB>
__device__ __forceinline__ void lp_rungemm(const bf16raw* __restrict__ sA,
                                           const bf16raw* __restrict__ bfbase,
                                           int wrow, int wcol, int lrow, int lquad,
                                           f32x4 (&acc)[2][4])
{
#pragma unroll
    for (int i = 0; i < 2; i++)
#pragma unroll
        for (int j = 0; j < 4; j++) acc[i][j] = (f32x4){0.f, 0.f, 0.f, 0.f};
    bf16x8 bb[16];
    lp_burst<CB>(bfbase, wcol, bb);
    SB();
    lp_mfma_all(sA, wrow, lrow, lquad, bb, acc);
}

// ---------------------------------------------------------------------------
// level half-burst helpers.  Wave w: coltiles w*2, w*2+1.
// ---------------------------------------------------------------------------
template<int G, int H>
__device__ __forceinline__ void load8(const bf16raw* __restrict__ bfbase, int w,
                                      bf16x8 (&bb)[8])
{
#pragma unroll
    for (int kt2 = 0; kt2 < 4; ++kt2)
#pragma unroll
        for (int jj = 0; jj < 2; ++jj)
            bb[kt2 * 2 + jj] = *(const bf16x8*)(bfbase +
                    (long)(((G * 8 + w * 2 + jj) * KTS + H * 4 + kt2) * 512));
}

// 4-ktile MFMA group, 2 row-frags (child phase / root).
template<int AB>
__device__ __forceinline__ void mfma4k(const bf16raw* __restrict__ sA, int lrow, int lquad,
                                       bf16x8 (&bb)[8], f32x4 (&acc)[2][2])
{
#pragma unroll
    for (int kt2 = 0; kt2 < 4; ++kt2) {
        bf16x8 af[2];
#pragma unroll
        for (int i = 0; i < 2; ++i)
            af[i] = *(const bf16x8*)&sA[(i * 16 + lrow) * SAW + (AB + kt2) * 32 + lquad * 8];
#pragma unroll
        for (int jj = 0; jj < 2; ++jj)
#pragma unroll
            for (int i = 0; i < 2; ++i)
                acc[i][jj] = __builtin_amdgcn_mfma_f32_16x16x32_bf16(af[i], bb[kt2 * 2 + jj], acc[i][jj], 0, 0, 0);
    }
}

// 4-ktile MFMA group, 1 row-frag (parent phase, 16 rows).
template<int AB>
__device__ __forceinline__ void mfma4k1(const bf16raw* __restrict__ sA, int lrow, int lquad,
                                        bf16x8 (&bb)[8], f32x4 (&acc)[2])
{
#pragma unroll
    for (int kt2 = 0; kt2 < 4; ++kt2) {
        bf16x8 af = *(const bf16x8*)&sA[lrow * SAW + (AB + kt2) * 32 + lquad * 8];
#pragma unroll
        for (int jj = 0; jj < 2; ++jj)
            acc[jj] = __builtin_amdgcn_mfma_f32_16x16x32_bf16(af, bb[kt2 * 2 + jj], acc[jj], 0, 0, 0);
    }
}

// ---------------------------------------------------------------------------
// k_leafpre: per-vocab leaf tables (h, c, logits via MFMA, lse).  (r15)
// ---------------------------------------------------------------------------
__global__ __launch_bounds__(256, 3) void k_leafpre(
    const bf16raw* __restrict__ embeds_bf,
    const bf16raw* __restrict__ Bfrag, const float* __restrict__ bias_cat,
    const bf16raw* __restrict__ WoutFrag, const float* __restrict__ bout,
    bf16raw* __restrict__ hc_leaf, float* __restrict__ lossv6, int nvtot)
{
    const int vbase = blockIdx.x * 64;
    int nv = nvtot - vbase;
    if (nv > 64) nv = 64;
    if (nv <= 0) return;

    __shared__ __align__(16) bf16raw sA[64 * 136];
    __shared__ __align__(16) bf16raw sT[64 * 136];
    __shared__ float sLg[64 * 5];

    const int t = threadIdx.x;

    {
        const int row = t >> 2;
        const int co = (t & 3) * 32;
        const int arow = (row < nv) ? row : 0;
        const bf16raw* ax = embeds_bf + (long)(vbase + arow) * 128;
        *(short8*)&sA[row * 136 + co]      = *(const short8*)(ax + co);
        *(short8*)&sA[row * 136 + co + 8]  = *(const short8*)(ax + co + 8);
        *(short8*)&sA[row * 136 + co + 16] = *(const short8*)(ax + co + 16);
        *(short8*)&sA[row * 136 + co + 24] = *(const short8*)(ax + co + 24);
    }

    const int lane = t & 63;
    const int w = t >> 6;
    const int wrow = (w & 1) * 32;
    const int wcol = (w >> 1) * 64;
    const int lrow = lane & 15;
    const int lquad = lane >> 4;

    __syncthreads();

    const bf16raw* bfbase = Bfrag + (long)lane * 8;

    float tval[2][4][4];
    f32x4 acc[2][4];

    lp_rungemm<0>(sA, bfbase, wrow, wcol, lrow, lquad, acc);
#pragma unroll
    for (int i = 0; i < 2; i++)
#pragma unroll
        for (int jj = 0; jj < 4; jj++) {
            const float b = bias_cat[wcol + jj * 16 + lrow];
#pragma unroll
            for (int r = 0; r < 4; r++) tval[i][jj][r] = sigm(acc[i][jj][r] + b);
        }
    lp_rungemm<1>(sA, bfbase, wrow, wcol, lrow, lquad, acc);
#pragma unroll
    for (int i = 0; i < 2; i++)
#pragma unroll
        for (int jj = 0; jj < 4; jj++) {
            const float b = bias_cat[128 + wcol + jj * 16 + lrow];
#pragma unroll
            for (int r = 0; r < 4; r++) tval[i][jj][r] *= fast_tanh(acc[i][jj][r] + b);
        }
#pragma unroll
    for (int i = 0; i < 2; i++)
#pragma unroll
        for (int jj = 0; jj < 4; jj++)
#pragma unroll
            for (int r = 0; r < 4; r++) {
                const int m = wrow + i * 16 + lquad * 4 + r;
                const int j = wcol + jj * 16 + lrow;
                sT[m * 136 + j] = f2bf(tval[i][jj][r]);
            }
#pragma unroll
    for (int i = 0; i < 2; i++)
#pragma unroll
        for (int jj = 0; jj < 4; jj++)
#pragma unroll
            for (int r = 0; r < 4; r++) tval[i][jj][r] = fast_tanh(tval[i][jj][r]);
    __syncthreads();
#pragma unroll
    for (int s = 0; s < 4; ++s) {
        int ci = t + 256 * s;
        int row = ci >> 4, c8 = (ci & 15) * 8;
        if (row < nv)
            *(short8*)(hc_leaf + (long)(vbase + row) * 256 + 128 + c8) = *(const short8*)&sT[row * 136 + c8];
    }
    lp_rungemm<2>(sA, bfbase, wrow, wcol, lrow, lquad, acc);
    __syncthreads();
#pragma unroll
    for (int i = 0; i < 2; i++)
#pragma unroll
        for (int jj = 0; jj < 4; jj++) {
            const float b = bias_cat[256 + wcol + jj * 16 + lrow];
#pragma unroll
            for (int r = 0; r < 4; r++) {
                const int m = wrow + i * 16 + lquad * 4 + r;
                const int j = wcol + jj * 16 + lrow;
                sT[m * 136 + j] = f2bf(sigm(acc[i][jj][r] + b) * tval[i][jj][r]);
            }
        }
    __syncthreads();
#pragma unroll
    for (int s = 0; s < 4; ++s) {
        int ci = t + 256 * s;
        int row = ci >> 4, c8 = (ci & 15) * 8;
        if (row < nv)
            *(short8*)(hc_leaf + (long)(vbase + row) * 256 + c8) = *(const short8*)&sT[row * 136 + c8];
    }
    {
        f32x4 lacc = (f32x4){0.f, 0.f, 0.f, 0.f};
#pragma unroll
        for (int kt = 0; kt < 4; ++kt) {
            bf16x8 bfr = *(const bf16x8*)(WoutFrag + (long)((kt * 64 + lane) * 8));
            bf16x8 af = *(const bf16x8*)&sT[(w * 16 + lrow) * 136 + kt * 32 + lquad * 8];
            lacc = __builtin_amdgcn_mfma_f32_16x16x32_bf16(af, bfr, lacc, 0, 0, 0);
        }
        if (lrow < 5) {
            const float bl = bout[lrow];
#pragma unroll
            for (int r = 0; r < 4; ++r)
                sLg[(w * 16 + lquad * 4 + r) * 5 + lrow] = lacc[r] + bl;
        }
    }
    __syncthreads();
    if (t < 64 && t < nv) {
        float lg[5], mx = -1e30f;
#pragma unroll
        for (int l = 0; l < 5; l++) {
            lg[l] = sLg[t * 5 + l];
            mx = fmaxf(mx, lg[l]);
        }
        float se = 0.f;
#pragma unroll
        for (int l = 0; l < 5; l++) se += __expf(lg[l] - mx);
        float lse = __logf(se) + mx;
        float* dst = lossv6 + (long)(vbase + t) * 6;
#pragma unroll
        for (int l = 0; l < 5; l++) dst[l] = lg[l];
        dst[5] = lse;
    }
}

// ---------------------------------------------------------------------------
// k_pair (r16): fused (even-child, odd-parent) level pair.  Block = 32 child
// nodes + their 16 parents.  Child h/c NEVER leave LDS (consumed by parent
// GEMM + in-block loss) — eliminates the even level's global h/c round trip
// and halves level dispatches (17 -> 8 pairs + root).  Blocks independent
// (full parallelism; no r8/r11-style grid serialization).
// ---------------------------------------------------------------------------
__global__ __launch_bounds__(256, 3) void k_pair(
    const bf16raw* __restrict__ embeds_bf, const int* __restrict__ words,
    const int* __restrict__ labels,
    bf16raw* __restrict__ h_all, bf16raw* __restrict__ c_all,
    const bf16raw* __restrict__ hc_leaf, const float* __restrict__ lossv6,
    const bf16raw* __restrict__ Bfrag, const bf16raw* __restrict__ WoutFrag,
    const float* __restrict__ bias_cat, const float* __restrict__ bout,
    float* __restrict__ partials,
    int offP, int nP, int leafkids)
{
    __shared__ __align__(16) bf16raw sA[32 * SAW];
    __shared__ __align__(16) bf16raw sCT[64 * 136];
    __shared__ float sLg[160];

    const int t = threadIdx.x;
    const int offC = 2 * offP + 1;       // child level offset
    const int nmC = 2 * nP;              // child level size
    const int m0C = blockIdx.x * 32;
    const int m0P = blockIdx.x * 16;

    const int lane = t & 63;
    const int w = t >> 6;
    const int lrow = lane & 15;
    const int lquad = lane >> 4;
    const bf16raw* bfbase = Bfrag + (long)lane * 8;

    // bias preload (gate order 0=i,1=u,2=o,3=f)
    float bias[4][2];
#pragma unroll
    for (int g = 0; g < 4; ++g)
#pragma unroll
        for (int jj = 0; jj < 2; ++jj)
            bias[g][jj] = bias_cat[g * 128 + w * 32 + jj * 16 + lrow];

    // =================== CHILD PHASE (32 nodes, even level) ===================
    {
        const int row = t >> 3;
        const int co = (t & 7) * 8;
        int mm = m0C + row; if (mm >= nmC) mm = nmC - 1;
        const long g = (long)offC + mm;
        const bf16raw* px = embeds_bf + (long)words[g] * 128;
        const bf16raw *p1, *p2;
        if (leafkids) {
            p1 = hc_leaf + (long)words[2 * g + 1] * 256;
            p2 = hc_leaf + (long)words[2 * g + 2] * 256;
        } else {
            p1 = h_all + (2 * g + 1) * 128;
            p2 = h_all + (2 * g + 2) * 128;
        }
        short8 vx0 = *(const short8*)(px + co);
        short8 vx1 = *(const short8*)(px + 64 + co);
        short8 h10 = *(const short8*)(p1 + co);
        short8 h11 = *(const short8*)(p1 + 64 + co);
        short8 h20 = *(const short8*)(p2 + co);
        short8 h21 = *(const short8*)(p2 + 64 + co);
        short8 hs0, hs1;
#pragma unroll
        for (int e = 0; e < 8; ++e) {
            hs0[e] = (short)f2bf(bf2f((bf16raw)(unsigned short)h10[e]) +
                                 bf2f((bf16raw)(unsigned short)h20[e]));
            hs1[e] = (short)f2bf(bf2f((bf16raw)(unsigned short)h11[e]) +
                                 bf2f((bf16raw)(unsigned short)h21[e]));
        }
        *(short8*)&sA[row * SAW + co]        = vx0;
        *(short8*)&sA[row * SAW + 64 + co]   = vx1;
        *(short8*)&sA[row * SAW + 128 + co]  = hs0;
        *(short8*)&sA[row * SAW + 192 + co]  = hs1;
        *(short8*)&sA[row * SAW + 256 + co]  = h10;
        *(short8*)&sA[row * SAW + 320 + co]  = h11;
        *(short8*)&sA[row * SAW + 384 + co]  = h20;
        *(short8*)&sA[row * SAW + 448 + co]  = h21;
    }
    {
        const int slot = t >> 2;
        const int cc8 = (t & 3) * 8;
        int mm = m0C + (slot >> 1); if (mm >= nmC) mm = nmC - 1;
        const long g = (long)offC + mm;
        const long cg = 2 * g + 1 + (slot & 1);
        const bf16raw* pc = leafkids ? (hc_leaf + (long)words[cg] * 256 + 128)
                                     : (c_all + cg * 128);
#pragma unroll
        for (int s = 0; s < 4; ++s)
            *(short8*)&sCT[slot * 136 + s * 32 + cc8] = *(const short8*)(pc + s * 32 + cc8);
    }
    __syncthreads();

    {
        f32x4 acc[2][2];
        f32x4 fx[2][2];
        float si[2][2][4];
        float cc[2][2][4];
        float hh[2][2][4];
        bf16x8 bbA[8], bbB[8];

#define ZACC() { _Pragma("unroll") for (int i_ = 0; i_ < 2; ++i_) \
                 _Pragma("unroll") for (int j_ = 0; j_ < 2; ++j_) \
                     acc[i_][j_] = (f32x4){0.f, 0.f, 0.f, 0.f}; }

        load8<0, 0>(bfbase, w, bbA);
        load8<0, 1>(bfbase, w, bbB);
        SB();
        ZACC();
        mfma4k<0>(sA, lrow, lquad, bbA, acc); SB();
        load8<1, 0>(bfbase, w, bbA); SB();
        mfma4k<4>(sA, lrow, lquad, bbB, acc); SB();
        load8<1, 1>(bfbase, w, bbB); SB();
#pragma unroll
        for (int i = 0; i < 2; ++i)
#pragma unroll
            for (int jj = 0; jj < 2; ++jj)
#pragma unroll
                for (int r = 0; r < 4; ++r)
                    si[i][jj][r] = sigm(acc[i][jj][r] + bias[0][jj]);
        ZACC();
        mfma4k<0>(sA, lrow, lquad, bbA, acc); SB();
        load8<3, 0>(bfbase, w, bbA); SB();
        mfma4k<4>(sA, lrow, lquad, bbB, acc); SB();
        load8<3, 1>(bfbase, w, bbB); SB();
#pragma unroll
        for (int i = 0; i < 2; ++i)
#pragma unroll
            for (int jj = 0; jj < 2; ++jj)
#pragma unroll
                for (int r = 0; r < 4; ++r)
                    cc[i][jj][r] = si[i][jj][r] * fast_tanh(acc[i][jj][r] + bias[1][jj]);
        ZACC();
        mfma4k<0>(sA, lrow, lquad, bbA, acc);
        SB();
#pragma unroll
        for (int i = 0; i < 2; ++i)
#pragma unroll
            for (int jj = 0; jj < 2; ++jj) fx[i][jj] = acc[i][jj];
        mfma4k<8>(sA, lrow, lquad, bbB, acc);
        SB();
        load8<2, 0>(bfbase, w, bbA);
        SB();
#pragma unroll
        for (int i = 0; i < 2; ++i)
#pragma unroll
            for (int jj = 0; jj < 2; ++jj) {
                const int j = w * 32 + jj * 16 + lrow;
#pragma unroll
                for (int r = 0; r < 4; ++r) {
                    const int m = i * 16 + lquad * 4 + r;
                    cc[i][jj][r] += sigm(acc[i][jj][r] + bias[3][jj]) * bf2f(sCT[(2 * m) * 136 + j]);
                }
            }
#pragma unroll
        for (int i = 0; i < 2; ++i)
#pragma unroll
            for (int jj = 0; jj < 2; ++jj) acc[i][jj] = fx[i][jj];
        mfma4k<12>(sA, lrow, lquad, bbB, acc);
        SB();
        load8<2, 1>(bfbase, w, bbB);
        SB();
#pragma unroll
        for (int i = 0; i < 2; ++i)
#pragma unroll
            for (int jj = 0; jj < 2; ++jj) {
                const int j = w * 32 + jj * 16 + lrow;
#pragma unroll
                for (int r = 0; r < 4; ++r) {
                    const int m = i * 16 + lquad * 4 + r;
                    cc[i][jj][r] += sigm(acc[i][jj][r] + bias[3][jj]) * bf2f(sCT[(2 * m + 1) * 136 + j]);
                }
            }
        ZACC();
        mfma4k<0>(sA, lrow, lquad, bbA, acc);
        mfma4k<4>(sA, lrow, lquad, bbB, acc);
        SB();
#pragma unroll
        for (int i = 0; i < 2; ++i)
#pragma unroll
            for (int jj = 0; jj < 2; ++jj)
#pragma unroll
                for (int r = 0; r < 4; ++r)
                    hh[i][jj][r] = sigm(acc[i][jj][r] + bias[2][jj]) * fast_tanh(cc[i][jj][r]);
#undef ZACC

        __syncthreads();   // all sCT grandchild-c reads done

        // child c -> sCT rows 0..31, child h -> rows 32..63 (NO global flush)
#pragma unroll
        for (int i = 0; i < 2; ++i)
#pragma unroll
            for (int jj = 0; jj < 2; ++jj) {
                const int j = w * 32 + jj * 16 + lrow;
#pragma unroll
                for (int r = 0; r < 4; ++r) {
                    const int m = i * 16 + lquad * 4 + r;
                    sCT[m * 136 + j] = f2bf(cc[i][jj][r]);
                    sCT[(32 + m) * 136 + j] = f2bf(hh[i][jj][r]);
                }
            }
    }
    __syncthreads();

    // ---- child logits (wave 0) ----
    if (w == 0) {
        f32x4 lacc[2];
        lacc[0] = (f32x4){0.f, 0.f, 0.f, 0.f};
        lacc[1] = (f32x4){0.f, 0.f, 0.f, 0.f};
#pragma unroll
        for (int kt = 0; kt < 4; ++kt) {
            bf16x8 bfr = *(const bf16x8*)(WoutFrag + (long)((kt * 64 + lane) * 8));
#pragma unroll
            for (int i = 0; i < 2; ++i) {
                bf16x8 af = *(const bf16x8*)&sCT[(32 + i * 16 + lrow) * 136 + kt * 32 + lquad * 8];
                lacc[i] = __builtin_amdgcn_mfma_f32_16x16x32_bf16(af, bfr, lacc[i], 0, 0, 0);
            }
        }
        if (lrow < 5) {
            const float bl = bout[lrow];
#pragma unroll
            for (int i = 0; i < 2; ++i)
#pragma unroll
                for (int r = 0; r < 4; ++r)
                    sLg[(i * 16 + lquad * 4 + r) * 5 + lrow] = lacc[i][r] + bl;
        }
    }
    __syncthreads();

    // ---- child loss (t<32) + PARENT A staging (all threads; reads sCT h,
    //      writes dead sA) ----
    if (t < 32 && m0C + t < nmC) {
        const long g = (long)offC + m0C + t;
        float lgv[5], mx = -1e30f;
#pragma unroll
        for (int l = 0; l < 5; ++l) {
            lgv[l] = sLg[t * 5 + l];
            mx = fmaxf(mx, lgv[l]);
        }
        float se = 0.f;
#pragma unroll
        for (int l = 0; l < 5; ++l) se += __expf(lgv[l] - mx);
        float lse = __logf(se) + mx;
        float lossNode = lse - lgv[labels[g]];
        if (leafkids) {
            const float* lv1 = lossv6 + (long)words[2 * g + 1] * 6;
            const float* lv2 = lossv6 + (long)words[2 * g + 2] * 6;
            lossNode += (lv1[5] - lv1[labels[2 * g + 1]])
                      + (lv2[5] - lv2[labels[2 * g + 2]]);
        }
        atomicAdd(&partials[(int)(g & 1023)], lossNode);
    }
    {
        const int rowP = t >> 4;             // 0..15
        const int co = (t & 15) * 8;         // 0..120
        int pp = m0P + rowP; if (pp >= nP) pp = nP - 1;
        const long gP = (long)offP + pp;
        const int dp = pp - m0P;             // clamped local parent
        const bf16raw* px = embeds_bf + (long)words[gP] * 128;
        short8 vx = *(const short8*)(px + co);
        short8 h1 = *(short8*)&sCT[(32 + 2 * dp) * 136 + co];
        short8 h2 = *(short8*)&sCT[(32 + 2 * dp + 1) * 136 + co];
        short8 hs;
#pragma unroll
        for (int e = 0; e < 8; ++e)
            hs[e] = (short)f2bf(bf2f((bf16raw)(unsigned short)h1[e]) +
                                bf2f((bf16raw)(unsigned short)h2[e]));
        *(short8*)&sA[rowP * SAW + co]       = vx;
        *(short8*)&sA[rowP * SAW + 128 + co] = hs;
        *(short8*)&sA[rowP * SAW + 256 + co] = h1;
        *(short8*)&sA[rowP * SAW + 384 + co] = h2;
    }
    __syncthreads();   // parent sA published; sCT c rows still valid

    // =================== PARENT PHASE (16 nodes, odd level) ===================
    {
        f32x4 acc[2];
        f32x4 fx[2];
        float si[2][4];
        float cc[2][4];
        float hh[2][4];
        bf16x8 bbA[8], bbB[8];

#define PZ() { acc[0] = (f32x4){0.f,0.f,0.f,0.f}; acc[1] = (f32x4){0.f,0.f,0.f,0.f}; }

        load8<0, 0>(bfbase, w, bbA);
        load8<0, 1>(bfbase, w, bbB);
        SB();
        PZ();
        mfma4k1<0>(sA, lrow, lquad, bbA, acc); SB();
        load8<1, 0>(bfbase, w, bbA); SB();
        mfma4k1<4>(sA, lrow, lquad, bbB, acc); SB();
        load8<1, 1>(bfbase, w, bbB); SB();
#pragma unroll
        for (int jj = 0; jj < 2; ++jj)
#pragma unroll
            for (int r = 0; r < 4; ++r)
                si[jj][r] = sigm(acc[jj][r] + bias[0][jj]);
        PZ();
        mfma4k1<0>(sA, lrow, lquad, bbA, acc); SB();
        load8<3, 0>(bfbase, w, bbA); SB();
        mfma4k1<4>(sA, lrow, lquad, bbB, acc); SB();
        load8<3, 1>(bfbase, w, bbB); SB();
#pragma unroll
        for (int jj = 0; jj < 2; ++jj)
#pragma unroll
            for (int r = 0; r < 4; ++r)
                cc[jj][r] = si[jj][r] * fast_tanh(acc[jj][r] + bias[1][jj]);
        PZ();
        mfma4k1<0>(sA, lrow, lquad, bbA, acc);
        SB();
        fx[0] = acc[0]; fx[1] = acc[1];
        mfma4k1<8>(sA, lrow, lquad, bbB, acc);
        SB();
        load8<2, 0>(bfbase, w, bbA);
        SB();
#pragma unroll
        for (int jj = 0; jj < 2; ++jj) {
            const int j = w * 32 + jj * 16 + lrow;
#pragma unroll
            for (int r = 0; r < 4; ++r) {
                const int m = lquad * 4 + r;
                cc[jj][r] += sigm(acc[jj][r] + bias[3][jj]) * bf2f(sCT[(2 * m) * 136 + j]);
            }
        }
        acc[0] = fx[0]; acc[1] = fx[1];
        mfma4k1<12>(sA, lrow, lquad, bbB, acc);
        SB();
        load8<2, 1>(bfbase, w, bbB);
        SB();
#pragma unroll
        for (int jj = 0; jj < 2; ++jj) {
            const int j = w * 32 + jj * 16 + lrow;
#pragma unroll
            for (int r = 0; r < 4; ++r) {
                const int m = lquad * 4 + r;
                cc[jj][r] += sigm(acc[jj][r] + bias[3][jj]) * bf2f(sCT[(2 * m + 1) * 136 + j]);
            }
        }
        PZ();
        mfma4k1<0>(sA, lrow, lquad, bbA, acc);
        mfma4k1<4>(sA, lrow, lquad, bbB, acc);
        SB();
#pragma unroll
        for (int jj = 0; jj < 2; ++jj)
#pragma unroll
            for (int r = 0; r < 4; ++r)
                hh[jj][r] = sigm(acc[jj][r] + bias[2][jj]) * fast_tanh(cc[jj][r]);
#undef PZ

        __syncthreads();   // all child-c reads done before overwrite

        // parent c -> sCT rows 0..15, parent h -> rows 16..31
#pragma unroll
        for (int jj = 0; jj < 2; ++jj) {
            const int j = w * 32 + jj * 16 + lrow;
#pragma unroll
            for (int r = 0; r < 4; ++r) {
                const int m = lquad * 4 + r;
                sCT[m * 136 + j] = f2bf(cc[jj][r]);
                sCT[(16 + m) * 136 + j] = f2bf(hh[jj][r]);
            }
        }
    }
    __syncthreads();

    // ---- flush parent c/h (coalesced, 2 chunks/thread) ----
#pragma unroll
    for (int q = 0; q < 2; ++q) {
        int ci = t + 256 * q;               // 0..511
        int row = ci >> 4;                  // 0..31
        int c8 = (ci & 15) * 8;
        int m = row & 15;
        if (m0P + m < nP) {
            bf16raw* dst = (row < 16) ? c_all : h_all;
            *(short8*)(dst + ((long)offP + m0P + m) * 128 + c8) = *(const short8*)&sCT[row * 136 + c8];
        }
    }

    // ---- parent logits (wave 0; h rows 16..31) ----
    if (w == 0) {
        f32x4 lacc = (f32x4){0.f, 0.f, 0.f, 0.f};
#pragma unroll
        for (int kt = 0; kt < 4; ++kt) {
            bf16x8 bfr = *(const bf16x8*)(WoutFrag + (long)((kt * 64 + lane) * 8));
            bf16x8 af = *(const bf16x8*)&sCT[(16 + lrow) * 136 + kt * 32 + lquad * 8];
            lacc = __builtin_amdgcn_mfma_f32_16x16x32_bf16(af, bfr, lacc, 0, 0, 0);
        }
        if (lrow < 5) {
            const float bl = bout[lrow];
#pragma unroll
            for (int r = 0; r < 4; ++r)
                sLg[(lquad * 4 + r) * 5 + lrow] = lacc[r] + bl;
        }
    }
    __syncthreads();

    // ---- parent loss (t<16) ----
    if (t < 16 && m0P + t < nP) {
        const long g = (long)offP + m0P + t;
        float lgv[5], mx = -1e30f;
#pragma unroll
        for (int l = 0; l < 5; ++l) {
            lgv[l] = sLg[t * 5 + l];
            mx = fmaxf(mx, lgv[l]);
        }
        float se = 0.f;
#pragma unroll
        for (int l = 0; l < 5; ++l) se += __expf(lgv[l] - mx);
        float lse = __logf(se) + mx;
        atomicAdd(&partials[(int)(g & 1023)], lse - lgv[labels[g]]);
    }
}

// ---------------------------------------------------------------------------
// k_level32 (root only): r15 body with isroot reduction.
// ---------------------------------------------------------------------------
__global__ __launch_bounds__(256, 3) void k_level32(
    const bf16raw* __restrict__ embeds_bf, const int* __restrict__ words,
    const int* __restrict__ labels,
    bf16raw* __restrict__ h_all, bf16raw* __restrict__ c_all,
    const bf16raw* __restrict__ hc_leaf, const float* __restrict__ lossv6,
    const bf16raw* __restrict__ Bfrag, const bf16raw* __restrict__ WoutFrag,
    const float* __restrict__ bias_cat, const float* __restrict__ bout,
    float* __restrict__ partials, float* __restrict__ out,
    int off, int nm, int leafkids, int isroot)
{
    __shared__ __align__(16) bf16raw sA[32 * SAW];
    __shared__ __align__(16) bf16raw sCT[64 * 136];
    __shared__ float sLg[168];

    const int t = threadIdx.x;
    const int m0 = blockIdx.x * 32;

    {
        const int row = t >> 3;
        const int co = (t & 7) * 8;
        int mm = m0 + row; if (mm >= nm) mm = nm - 1;
        const long g = (long)off + mm;
        const bf16raw* px = embeds_bf + (long)words[g] * 128;
        const bf16raw *p1, *p2;
        if (leafkids) {
            p1 = hc_leaf + (long)words[2 * g + 1] * 256;
            p2 = hc_leaf + (long)words[2 * g + 2] * 256;
        } else {
            p1 = h_all + (2 * g + 1) * 128;
            p2 = h_all + (2 * g + 2) * 128;
        }
        short8 vx0 = *(const short8*)(px + co);
        short8 vx1 = *(const short8*)(px + 64 + co);
        short8 h10 = *(const short8*)(p1 + co);
        short8 h11 = *(const short8*)(p1 + 64 + co);
        short8 h20 = *(const short8*)(p2 + co);
        short8 h21 = *(const short8*)(p2 + 64 + co);
        short8 hs0, hs1;
#pragma unroll
        for (int e = 0; e < 8; ++e) {
            hs0[e] = (short)f2bf(bf2f((bf16raw)(unsigned short)h10[e]) +
                                 bf2f((bf16raw)(unsigned short)h20[e]));
            hs1[e] = (short)f2bf(bf2f((bf16raw)(unsigned short)h11[e]) +
                                 bf2f((bf16raw)(unsigned short)h21[e]));
        }
        *(short8*)&sA[row * SAW + co]        = vx0;
        *(short8*)&sA[row * SAW + 64 + co]   = vx1;
        *(short8*)&sA[row * SAW + 128 + co]  = hs0;
        *(short8*)&sA[row * SAW + 192 + co]  = hs1;
        *(short8*)&sA[row * SAW + 256 + co]  = h10;
        *(short8*)&sA[row * SAW + 320 + co]  = h11;
        *(short8*)&sA[row * SAW + 384 + co]  = h20;
        *(short8*)&sA[row * SAW + 448 + co]  = h21;
    }
    {
        const int slot = t >> 2;
        const int cc8 = (t & 3) * 8;
        int mm = m0 + (slot >> 1); if (mm >= nm) mm = nm - 1;
        const long g = (long)off + mm;
        const long cg = 2 * g + 1 + (slot & 1);
        const bf16raw* pc = leafkids ? (hc_leaf + (long)words[cg] * 256 + 128)
                                     : (c_all + cg * 128);
#pragma unroll
        for (int s = 0; s < 4; ++s)
            *(short8*)&sCT[slot * 136 + s * 32 + cc8] = *(const short8*)(pc + s * 32 + cc8);
    }

    const int lane = t & 63;
    const int w = t >> 6;
    const int lrow = lane & 15;
    const int lquad = lane >> 4;

    float bias[4][2];
#pragma unroll
    for (int g = 0; g < 4; ++g)
#pragma unroll
        for (int jj = 0; jj < 2; ++jj)
            bias[g][jj] = bias_cat[g * 128 + w * 32 + jj * 16 + lrow];

    __syncthreads();

    const bf16raw* bfbase = Bfrag + (long)lane * 8;

    f32x4 acc[2][2];
    f32x4 fx[2][2];
    float si[2][2][4];
    float cc[2][2][4];
    float hh[2][2][4];
    bf16x8 bbA[8], bbB[8];

#define ZACC() { _Pragma("unroll") for (int i_ = 0; i_ < 2; ++i_) \
                 _Pragma("unroll") for (int j_ = 0; j_ < 2; ++j_) \
                     acc[i_][j_] = (f32x4){0.f, 0.f, 0.f, 0.f}; }

    load8<0, 0>(bfbase, w, bbA);
    load8<0, 1>(bfbase, w, bbB);
    SB();
    ZACC();
    mfma4k<0>(sA, lrow, lquad, bbA, acc); SB();
    load8<1, 0>(bfbase, w, bbA); SB();
    mfma4k<4>(sA, lrow, lquad, bbB, acc); SB();
    load8<1, 1>(bfbase, w, bbB); SB();
#pragma unroll
    for (int i = 0; i < 2; ++i)
#pragma unroll
        for (int jj = 0; jj < 2; ++jj)
#pragma unroll
            for (int r = 0; r < 4; ++r)
                si[i][jj][r] = sigm(acc[i][jj][r] + bias[0][jj]);
    ZACC();
    mfma4k<0>(sA, lrow, lquad, bbA, acc); SB();
    load8<3, 0>(bfbase, w, bbA); SB();
    mfma4k<4>(sA, lrow, lquad, bbB, acc); SB();
    load8<3, 1>(bfbase, w, bbB); SB();
#pragma unroll
    for (int i = 0; i < 2; ++i)
#pragma unroll
        for (int jj = 0; jj < 2; ++jj)
#pragma unroll
            for (int r = 0; r < 4; ++r)
                cc[i][jj][r] = si[i][jj][r] * fast_tanh(acc[i][jj][r] + bias[1][jj]);
    ZACC();
    mfma4k<0>(sA, lrow, lquad, bbA, acc);
    SB();
#pragma unroll
    for (int i = 0; i < 2; ++i)
#pragma unroll
        for (int jj = 0; jj < 2; ++jj) fx[i][jj] = acc[i][jj];
    mfma4k<8>(sA, lrow, lquad, bbB, acc);
    SB();
    load8<2, 0>(bfbase, w, bbA);
    SB();
#pragma unroll
    for (int i = 0; i < 2; ++i)
#pragma unroll
        for (int jj = 0; jj < 2; ++jj) {
            const int j = w * 32 + jj * 16 + lrow;
#pragma unroll
            for (int r = 0; r < 4; ++r) {
                const int m = i * 16 + lquad * 4 + r;
                cc[i][jj][r] += sigm(acc[i][jj][r] + bias[3][jj]) * bf2f(sCT[(2 * m) * 136 + j]);
            }
        }
#pragma unroll
    for (int i = 0; i < 2; ++i)
#pragma unroll
        for (int jj = 0; jj < 2; ++jj) acc[i][jj] = fx[i][jj];
    mfma4k<12>(sA, lrow, lquad, bbB, acc);
    SB();
    load8<2, 1>(bfbase, w, bbB);
    SB();
#pragma unroll
    for (int i = 0; i < 2; ++i)
#pragma unroll
        for (int jj = 0; jj < 2; ++jj) {
            const int j = w * 32 + jj * 16 + lrow;
#pragma unroll
            for (int r = 0; r < 4; ++r) {
                const int m = i * 16 + lquad * 4 + r;
                cc[i][jj][r] += sigm(acc[i][jj][r] + bias[3][jj]) * bf2f(sCT[(2 * m + 1) * 136 + j]);
            }
        }
    ZACC();
    mfma4k<0>(sA, lrow, lquad, bbA, acc);
    mfma4k<4>(sA, lrow, lquad, bbB, acc);
    SB();
#pragma unroll
    for (int i = 0; i < 2; ++i)
#pragma unroll
        for (int jj = 0; jj < 2; ++jj)
#pragma unroll
            for (int r = 0; r < 4; ++r)
                hh[i][jj][r] = sigm(acc[i][jj][r] + bias[2][jj]) * fast_tanh(cc[i][jj][r]);
#undef ZACC

    __syncthreads();

#pragma unroll
    for (int i = 0; i < 2; ++i)
#pragma unroll
        for (int jj = 0; jj < 2; ++jj) {
            const int j = w * 32 + jj * 16 + lrow;
#pragma unroll
            for (int r = 0; r < 4; ++r) {
                const int m = i * 16 + lquad * 4 + r;
                sCT[m * 136 + j] = f2bf(cc[i][jj][r]);
                sCT[(32 + m) * 136 + j] = f2bf(hh[i][jj][r]);
            }
        }
    __syncthreads();

#pragma unroll
    for (int q = 0; q < 4; ++q) {
        int ci = t + 256 * q;
        int row = ci >> 4;
        int c8 = (ci & 15) * 8;
        int m = row & 31;
        if (m0 + m < nm) {
            bf16raw* dst = (row < 32) ? c_all : h_all;
            *(short8*)(dst + ((long)off + m0 + m) * 128 + c8) = *(const short8*)&sCT[row * 136 + c8];
        }
    }

    if (w == 0) {
        f32x4 lacc[2];
        lacc[0] = (f32x4){0.f, 0.f, 0.f, 0.f};
        lacc[1] = (f32x4){0.f, 0.f, 0.f, 0.f};
#pragma unroll
        for (int kt = 0; kt < 4; ++kt) {
            bf16x8 bfr = *(const bf16x8*)(WoutFrag + (long)((kt * 64 + lane) * 8));
#pragma unroll
            for (int i = 0; i < 2; ++i) {
                bf16x8 af = *(const bf16x8*)&sCT[(32 + i * 16 + lrow) * 136 + kt * 32 + lquad * 8];
                lacc[i] = __builtin_amdgcn_mfma_f32_16x16x32_bf16(af, bfr, lacc[i], 0, 0, 0);
            }
        }
        if (lrow < 5) {
            const float bl = bout[lrow];
#pragma unroll
            for (int i = 0; i < 2; ++i)
#pragma unroll
                for (int r = 0; r < 4; ++r)
                    sLg[(i * 16 + lquad * 4 + r) * 5 + lrow] = lacc[i][r] + bl;
        }
    }
    __syncthreads();

    if (t < 32 && m0 + t < nm) {
        const long g = (long)off + m0 + t;
        float lgv[5], mx = -1e30f;
#pragma unroll
        for (int l = 0; l < 5; ++l) {
            lgv[l] = sLg[t * 5 + l];
            mx = fmaxf(mx, lgv[l]);
        }
        float se = 0.f;
#pragma unroll
        for (int l = 0; l < 5; ++l) se += __expf(lgv[l] - mx);
        float lse = __logf(se) + mx;
        float lossNode = lse - lgv[labels[g]];
        if (leafkids) {
            const float* lv1 = lossv6 + (long)words[2 * g + 1] * 6;
            const float* lv2 = lossv6 + (long)words[2 * g + 2] * 6;
            lossNode += (lv1[5] - lv1[labels[2 * g + 1]])
                      + (lv2[5] - lv2[labels[2 * g + 2]]);
        }
        if (isroot) {
            sLg[164] = lossNode;
#pragma unroll
            for (int l = 0; l < 5; ++l) out[l] = lgv[l] - lse;
        } else {
            atomicAdd(&partials[(int)(g & 1023)], lossNode);
        }
    }

    if (isroot) {
        __syncthreads();
        float s = 0.f;
        for (int i2 = t; i2 < 1024; i2 += 256) s += partials[i2];
#pragma unroll
        for (int d = 32; d > 0; d >>= 1) s += __shfl_down(s, d);
        if ((t & 63) == 0) sLg[160 + (t >> 6)] = s;
        __syncthreads();
        if (t == 0)
            out[5] = sLg[160] + sLg[161] + sLg[162] + sLg[163] + sLg[164];
    }
}

// ---------------------------------------------------------------------------
extern "C" void kernel_launch(void* const* d_in, const int* in_sizes, int n_in,
                              void* d_out, int out_size, void* d_ws, size_t ws_size,
                              hipStream_t stream)
{
    const float* embeds = (const float*)d_in[0];
    const int* words = (const int*)d_in[1];
    const int* labels = (const int*)d_in[2];
    const float* Wix = (const float*)d_in[5],  *bix  = (const float*)d_in[6];
    const float* Wih = (const float*)d_in[7],  *bih  = (const float*)d_in[8];
    const float* Wfx = (const float*)d_in[9],  *bfx  = (const float*)d_in[10];
    const float* Wfh = (const float*)d_in[11], *bfh  = (const float*)d_in[12];
    const float* Wox = (const float*)d_in[13], *box_ = (const float*)d_in[14];
    const float* Woh = (const float*)d_in[15], *boh  = (const float*)d_in[16];
    const float* Wux = (const float*)d_in[17], *bux  = (const float*)d_in[18];
    const float* Wuh = (const float*)d_in[19], *buh  = (const float*)d_in[20];
    const float* Wout = (const float*)d_in[21], *bout = (const float*)d_in[22];
    float* out = (float*)d_out;

    char* ws = (char*)d_ws;
    const size_t treeElems = (size_t)NINT * 128;
    bf16raw* h_all = (bf16raw*)ws;
    bf16raw* c_all = h_all + treeElems;
    bf16raw* embeds_bf = c_all + treeElems;
    bf16raw* Bfrag = embeds_bf + (size_t)NVOCAB * 128;
    bf16raw* WoutFrag = Bfrag + 4 * 8 * KTS * 512;
    bf16raw* hc_leaf = WoutFrag + 4 * 64 * 8;
    float* lossv6 = (float*)(hc_leaf + (size_t)NVOCAB * 256);
    float* bias_cat = lossv6 + (size_t)NVOCAB * 6;
    float* partials = bias_cat + 512;

    k_prep_all<<<NEMB + 528 + 1, 256, 0, stream>>>(
        embeds, Wix, bix, Wih, bih, Wfx, bfx, Wfh, bfh,
        Wox, box_, Woh, boh, Wux, bux, Wuh, buh, Wout,
        embeds_bf, Bfrag, WoutFrag, bias_cat, partials);

    k_leafpre<<<(NVOCAB + 63) / 64, 256, 0, stream>>>(
        embeds_bf, Bfrag, bias_cat, WoutFrag, bout, hc_leaf, lossv6, NVOCAB);

    // fused level pairs: parent odd levels 15,13,...,1 (child = parent+1)
    for (int l = DEPTH - 3; l >= 1; l -= 2) {
        const int nP = 1 << l;
        k_pair<<<dim3((nP + 15) / 16), 256, 0, stream>>>(
            embeds_bf, words, labels, h_all, c_all, hc_leaf, lossv6,
            Bfrag, WoutFrag, bias_cat, bout, partials,
            nP - 1, nP, (l == DEPTH - 3) ? 1 : 0);
    }
    // root (level 0)
    k_level32<<<dim3(1), 256, 0, stream>>>(
        embeds_bf, words, labels, h_all, c_all, hc_leaf, lossv6,
        Bfrag, WoutFrag, bias_cat, bout, partials, out,
        0, 1, 0, 1);
}